// Round 9
// baseline (715.807 us; speedup 1.0000x reference)
//
#include <hip/hip_runtime.h>
#include <hip/hip_bf16.h>
#include <stdint.h>

typedef __bf16 bf16_t;
typedef bf16_t bf16x8 __attribute__((ext_vector_type(8)));
typedef float f32x4 __attribute__((ext_vector_type(4)));

static constexpr int B_TOK  = 4096;
static constexpr int E_DIM  = 1024;
static constexpr int N_EXPC = 8;
static constexpr int HID    = 4096;
static constexpr int IMGSZ  = 4096;
static constexpr int NSLOT  = 2 * B_TOK;
static constexpr int NTIL   = 71;          // max 128-row tiles: 64 + 7 remainder tiles

#define DEVI __device__ __forceinline__

DEVI int imin(int a, int b) { return a < b ? a : b; }

DEVI uint16_t f2bf(float f) {
  union { float f; uint32_t u; } v; v.f = f;
  uint32_t u = v.u;
  return (uint16_t)((u + 0x7FFFu + ((u >> 16) & 1u)) >> 16);
}

DEVI void gload_lds16(const void* g, void* l) {
  __builtin_amdgcn_global_load_lds((const __attribute__((address_space(1))) void*)g,
                                   (__attribute__((address_space(3))) void*)l, 16, 0, 0);
}

template<int N> DEVI void waitv() {
  if constexpr (N == 0)       asm volatile("s_waitcnt vmcnt(0)" ::: "memory");
  else if constexpr (N == 3)  asm volatile("s_waitcnt vmcnt(3)" ::: "memory");
  else if constexpr (N == 4)  asm volatile("s_waitcnt vmcnt(4)" ::: "memory");
  else if constexpr (N == 10) asm volatile("s_waitcnt vmcnt(10)" ::: "memory");
}

#define BAR() do { __builtin_amdgcn_sched_barrier(0); __builtin_amdgcn_s_barrier(); \
                   __builtin_amdgcn_sched_barrier(0); } while (0)

#define MFMA16(a, b, c) __builtin_amdgcn_mfma_f32_16x16x32_bf16((a), (b), (c), 0, 0, 0)

// ---------------- transpose + convert: f32 [R][C] -> bf16 [C][R], 64x64 tiles ----------------
__global__ __launch_bounds__(256)
void transpose64(const float* __restrict__ in, uint16_t* __restrict__ out, int R, int C)
{
  __shared__ float tile[64][65];
  size_t off = (size_t)blockIdx.z * (size_t)R * (size_t)C;
  int c0 = blockIdx.x * 64, r0 = blockIdx.y * 64;
  int t = threadIdx.x;
  #pragma unroll
  for (int i = 0; i < 4; ++i) {               // f32x4 vectorized reads
    int rr = i * 16 + (t >> 4), c4 = (t & 15) * 4;
    f32x4 v = *(const f32x4*)&in[off + (size_t)(r0 + rr) * C + c0 + c4];
    tile[rr][c4 + 0] = v[0]; tile[rr][c4 + 1] = v[1];
    tile[rr][c4 + 2] = v[2]; tile[rr][c4 + 3] = v[3];
  }
  __syncthreads();
  #pragma unroll
  for (int i = 0; i < 8; ++i) {
    int c = i * 8 + (t >> 5), j = t & 31;
    ushort2 w;
    w.x = f2bf(tile[2 * j][c]);
    w.y = f2bf(tile[2 * j + 1][c]);
    *(ushort2*)&out[off + (size_t)(c0 + c) * R + r0 + 2 * j] = w;
  }
}

// ================= expert GEMM: 128x128, 2-buffer depth-1 counted-vmcnt, 5 blocks/CU ==========
// C[M,N] = A[M,K] @ BT[N,K]^T (+bias, +activation)
// EPI: 0 = raw f32 split-K partial (no bias), 3 = bias + gelu(exp-form) -> bf16
// TILED: 1D supertile raster + XCD swizzle over compact expert tile table meta[].
template<int BN, int EPI, bool GATHER, int NT, int KSPLIT>
__global__ __launch_bounds__(256, 5)
void gemm_p(const uint16_t* __restrict__ Ab, int lda,
            const uint16_t* __restrict__ BT, void* __restrict__ Cv, int ldc,
            const float* __restrict__ bias, int K,
            const int* __restrict__ meta, const int* __restrict__ perm,
            size_t bStride, int biasStride, size_t cPlane)
{
  constexpr int HN = BN / 2, FN = BN / 32;
  constexpr int OPS = (BN == 128 ? 4 : 3);
  constexpr int NT2 = NT * KSPLIT;
  constexpr int TOTAL = NTIL * NT2, Q = TOTAL / 8, FULLB = 64 * NT2;
  int bid = blockIdx.x;
  int wg = (bid & 7) * Q + (bid >> 3);            // XCD swizzle
  int mtile, nt2;
  if (wg < FULLB) { int rem = wg % (8 * NT2); mtile = (wg / (8 * NT2)) * 8 + (rem & 7); nt2 = rem >> 3; }
  else            { int rem = wg - FULLB;     mtile = 64 + rem % 7;                     nt2 = rem / 7; }
  if (mtile >= meta[0]) return;
  int nt = nt2 % NT, kc = nt2 / NT;
  int e = meta[1 + 3 * mtile], rowBase = meta[2 + 3 * mtile], rows = meta[3 + 3 * mtile];
  int Kc = K / KSPLIT, k0 = kc * Kc;
  const uint16_t* Bt = BT + (size_t)e * bStride;
  const float* bi = bias + (size_t)e * (size_t)biasStride;

  constexpr int ABUF = 8192;
  constexpr int BBUF = (BN == 128) ? 8192 : 4096;
  __shared__ __align__(16) char sAraw[2 * ABUF];
  __shared__ __align__(16) char sBraw[2 * BBUF];

  int t = threadIdx.x, wave = t >> 6, lane = t & 63;
  int wr = wave >> 1, wc = wave & 1;

  int rB = t >> 2;
  int slB = ((t & 3) ^ (rB & 3)) * 8;
  const uint16_t* gB0 = Bt + (size_t)(nt * BN + rB) * K + k0 + slB;
  const uint16_t* gB1 = Bt + (size_t)(nt * BN + rB + 64) * K + k0 + slB;  // BN==128 only

  int r0 = t >> 2, r1 = r0 + 64;
  int sl = ((t & 3) ^ (r0 & 3)) * 8;
  int rr0 = imin(r0, rows - 1), rr1 = imin(r1, rows - 1);
  int car0 = GATHER ? perm[rowBase + rr0] : rowBase + rr0;
  int car1 = GATHER ? perm[rowBase + rr1] : rowBase + rr1;
  const uint16_t* gA0 = Ab + (size_t)car0 * lda + k0 + sl;
  const uint16_t* gA1 = Ab + (size_t)car1 * lda + k0 + sl;

  char* laW = sAraw + wave * 1024;
  char* lbW = sBraw + wave * 1024;
  auto STAGE = [&](int kt, int c) {
    int ko = kt << 5;
    char* la = laW + c * ABUF;
    char* lb = lbW + c * BBUF;
    gload_lds16(gA0 + ko, la);
    gload_lds16(gA1 + ko, la + 4096);
    gload_lds16(gB0 + ko, lb);
    if constexpr (BN == 128) gload_lds16(gB1 + ko, lb + 4096);
  };

  f32x4 acc[4][FN];
  #pragma unroll
  for (int m = 0; m < 4; m++)
    #pragma unroll
    for (int n = 0; n < FN; n++)
      acc[m][n] = f32x4{0.f, 0.f, 0.f, 0.f};

  STAGE(0, 0);

  int fr = lane & 15;
  int rdoff = ((lane >> 4) ^ (lane & 3)) * 16;
  int nk = Kc >> 5;

  for (int kt = 0; kt < nk; ++kt) {
    int b = kt & 1, nb = b ^ 1;
    bool more = kt + 1 < nk;
    if (more) { STAGE(kt + 1, nb); waitv<OPS>(); }   // tile kt retired; kt+1 in flight
    else waitv<0>();
    BAR();

    const char* bA = sAraw + b * ABUF;
    const char* bB = sBraw + b * BBUF;
    bf16x8 af[4], bfr[FN];
    #pragma unroll
    for (int m = 0; m < 4; m++)
      af[m] = *(const bf16x8*)(bA + (wr * 64 + m * 16 + fr) * 64 + rdoff);
    #pragma unroll
    for (int n = 0; n < FN; n++)
      bfr[n] = *(const bf16x8*)(bB + (wc * HN + n * 16 + fr) * 64 + rdoff);
    #pragma unroll
    for (int m = 0; m < 4; m++)
      #pragma unroll
      for (int n = 0; n < FN; n++)
        acc[m][n] = MFMA16(af[m], bfr[n], acc[m][n]);

    BAR();
  }

  // epilogue: C/D layout col=lane&15, row=(lane>>4)*4+reg (m89-verified)
  #pragma unroll
  for (int m = 0; m < 4; m++) {
    int lrow = wr * 64 + m * 16 + (lane >> 4) * 4;
    #pragma unroll
    for (int n = 0; n < FN; n++) {
      int col = nt * BN + wc * HN + n * 16 + (lane & 15);
      float bval = (EPI == 3) ? bi[col] : 0.f;
      #pragma unroll
      for (int r = 0; r < 4; r++) {
        int lr = lrow + r;
        if (lr >= rows) continue;
        float v = acc[m][n][r] + bval;
        size_t cr = (size_t)kc * cPlane + (size_t)(rowBase + lr) * ldc + col;
        if (EPI == 3) {   // gelu(tanh) == v * sigmoid(1.5957691*(v + 0.044715 v^3))
          float u = v + 0.044715f * v * v * v;
          v = v / (1.f + __expf(-1.5957691216057308f * u));
          ((uint16_t*)Cv)[cr] = f2bf(v);
        } else {
          ((float*)Cv)[cr] = v;
        }
      }
    }
  }
}

// ================= enc/img GEMM: reg-A streaming (memory-bound regime) =================
template<int SPLITK>
__global__ __launch_bounds__(256, 3)
void gemm_encR(const float* __restrict__ F0, const float* __restrict__ F1,
               const float* __restrict__ F2, int lda,
               const uint16_t* __restrict__ BT, float* __restrict__ P, int K)
{
  int z = blockIdx.z, br = z / SPLITK, kc = z % SPLITK;
  const float* Af = (br == 0) ? F0 : (br == 1) ? F1 : F2;
  int Kc = K / SPLITK, k0 = kc * Kc;
  int rowBase = blockIdx.x * 64, nt = blockIdx.y;

  __shared__ __align__(16) char sB[3 * 8192];
  int t = threadIdx.x, wave = t >> 6, lane = t & 63;
  int fr = lane & 15, q4 = lane >> 4;

  const float* gA = Af + (size_t)(rowBase + wave * 16 + fr) * lda + k0 + q4 * 8;

  int rloc = t >> 2;
  int ssw = ((t & 3) ^ (rloc & 3)) * 8;
  const uint16_t* gB0 = BT + (size_t)(nt * 128 + rloc) * K + k0 + ssw;
  const uint16_t* gB1 = gB0 + (size_t)64 * K;

  auto STB = [&](int kt, int c) {
    gload_lds16(gB0 + kt * 32, sB + c * 8192 + wave * 1024);
    gload_lds16(gB1 + kt * 32, sB + c * 8192 + 4096 + wave * 1024);
  };

  f32x4 acc[8];
  #pragma unroll
  for (int n = 0; n < 8; ++n) acc[n] = f32x4{0.f, 0.f, 0.f, 0.f};

  int nk = Kc >> 5;
  STB(0, 0); STB(1, 1);
  f32x4 aE0 = *(const f32x4*)(gA),      aE1 = *(const f32x4*)(gA + 4);
  f32x4 aO0 = *(const f32x4*)(gA + 32), aO1 = *(const f32x4*)(gA + 36);
  int c0 = 0, c2 = 2;
  int bRow = (q4 ^ (fr & 3)) * 16;

  auto step = [&](int kt, f32x4& aX0, f32x4& aX1) {
    bool m2 = kt + 2 < nk;
    if (m2) STB(kt + 2, c2);
    bf16x8 a;
    a[0] = (bf16_t)aX0[0]; a[1] = (bf16_t)aX0[1]; a[2] = (bf16_t)aX0[2]; a[3] = (bf16_t)aX0[3];
    a[4] = (bf16_t)aX1[0]; a[5] = (bf16_t)aX1[1]; a[6] = (bf16_t)aX1[2]; a[7] = (bf16_t)aX1[3];
    int kp = m2 ? kt + 2 : kt;
    aX0 = *(const f32x4*)(gA + kp * 32);
    aX1 = *(const f32x4*)(gA + kp * 32 + 4);
    if (m2) waitv<10>(); else waitv<0>();
    BAR();
    const char* bb = sB + c0 * 8192;
    bf16x8 bfr[8];
    #pragma unroll
    for (int n = 0; n < 8; ++n)
      bfr[n] = *(const bf16x8*)(bb + n * 1024 + fr * 64 + bRow);
    #pragma unroll
    for (int n = 0; n < 8; ++n) acc[n] = MFMA16(a, bfr[n], acc[n]);
    BAR();
    c0 = (c0 == 2) ? 0 : c0 + 1;
    c2 = (c2 == 2) ? 0 : c2 + 1;
  };

  for (int kt = 0; kt < nk; kt += 2) {
    step(kt, aE0, aE1);
    step(kt + 1, aO0, aO1);
  }

  #pragma unroll
  for (int n = 0; n < 8; ++n) {
    int col = nt * 128 + n * 16 + fr;
    #pragma unroll
    for (int r = 0; r < 4; ++r) {
      int row = rowBase + wave * 16 + q4 * 4 + r;
      P[((size_t)z * B_TOK + row) * 256 + col] = acc[n][r];
    }
  }
}

// reduce split-K partials + bias (+silu) -> bf16 columns of xbf
template<int SK, bool SILU>
__global__ __launch_bounds__(256)
void redu_k(const float* __restrict__ P, const float* __restrict__ bias,
            uint16_t* __restrict__ xb, int colBase)
{
  int br = blockIdx.y;
  int row = blockIdx.x * 4 + (threadIdx.x >> 6);
  int c4 = (threadIdx.x & 63) * 4;
  f32x4 s = *(const f32x4*)&bias[c4];
  const float* p = P + ((size_t)br * SK * B_TOK + row) * 256 + c4;
  #pragma unroll
  for (int kc = 0; kc < SK; ++kc)
    s += *(const f32x4*)(p + (size_t)kc * B_TOK * 256);
  if (SILU) {
    #pragma unroll
    for (int j = 0; j < 4; ++j) s[j] = s[j] / (1.f + __expf(-s[j]));
  }
  ushort4 o;
  o.x = f2bf(s[0]); o.y = f2bf(s[1]); o.z = f2bf(s[2]); o.w = f2bf(s[3]);
  *(ushort4*)&xb[(size_t)row * E_DIM + colBase + br * 256 + c4] = o;
}

// ---------------- gate-path fold (all f32, parallelized) ----------------
__global__ __launch_bounds__(256)
void bvwo_k(const float* __restrict__ bv, const float* __restrict__ Wo,
            float* __restrict__ part)
{
  int b = blockIdx.x, t = threadIdx.x;
  f32x4 acc = {0.f, 0.f, 0.f, 0.f};
  for (int k = b * 128; k < b * 128 + 128; ++k) {
    float s = bv[k];
    f32x4 w = *(const f32x4*)&Wo[(size_t)k * E_DIM + t * 4];
    acc[0] = __builtin_fmaf(s, w[0], acc[0]);
    acc[1] = __builtin_fmaf(s, w[1], acc[1]);
    acc[2] = __builtin_fmaf(s, w[2], acc[2]);
    acc[3] = __builtin_fmaf(s, w[3], acc[3]);
  }
  *(f32x4*)&part[(size_t)b * E_DIM + t * 4] = acc;
}

__global__ void t1red_k(const float* __restrict__ part, const float* __restrict__ bo,
                        float* __restrict__ t1)
{
  int j = blockIdx.x * 256 + threadIdx.x;
  float s = bo[j];
  for (int b = 0; b < 8; ++b) s += part[(size_t)b * E_DIM + j];
  t1[j] = s;
}

__global__ __launch_bounds__(256)
void matf_k(const float* __restrict__ W, const float* __restrict__ G,
            float* __restrict__ out)
{
  int k = blockIdx.x * 4 + (threadIdx.x >> 6);
  int lane = threadIdx.x & 63;
  float a0 = 0.f, a1 = 0.f, a2 = 0.f, a3 = 0.f, a4 = 0.f, a5 = 0.f, a6 = 0.f, a7 = 0.f;
  for (int m = lane; m < E_DIM; m += 64) {
    float w = W[(size_t)k * E_DIM + m];
    const float* gm = &G[m * 8];
    a0 = __builtin_fmaf(w, gm[0], a0); a1 = __builtin_fmaf(w, gm[1], a1);
    a2 = __builtin_fmaf(w, gm[2], a2); a3 = __builtin_fmaf(w, gm[3], a3);
    a4 = __builtin_fmaf(w, gm[4], a4); a5 = __builtin_fmaf(w, gm[5], a5);
    a6 = __builtin_fmaf(w, gm[6], a6); a7 = __builtin_fmaf(w, gm[7], a7);
  }
  #pragma unroll
  for (int off = 32; off; off >>= 1) {
    a0 += __shfl_xor(a0, off); a1 += __shfl_xor(a1, off);
    a2 += __shfl_xor(a2, off); a3 += __shfl_xor(a3, off);
    a4 += __shfl_xor(a4, off); a5 += __shfl_xor(a5, off);
    a6 += __shfl_xor(a6, off); a7 += __shfl_xor(a7, off);
  }
  if (lane == 0) {
    float* o = &out[k * 8];
    o[0] = a0; o[1] = a1; o[2] = a2; o[3] = a3;
    o[4] = a4; o[5] = a5; o[6] = a6; o[7] = a7;
  }
}

__global__ __launch_bounds__(512)
void gbias_k(const float* __restrict__ t1, const float* __restrict__ Wg,
             const float* __restrict__ bg, float* __restrict__ gb)
{
  int e = threadIdx.x >> 6, lane = threadIdx.x & 63;
  float s = 0.f;
  for (int m = lane; m < E_DIM; m += 64) s = __builtin_fmaf(t1[m], Wg[m * 8 + e], s);
  #pragma unroll
  for (int off = 32; off; off >>= 1) s += __shfl_xor(s, off);
  if (lane == 0) gb[e] = s + bg[e];
}

// ---------------- gate: logits -> softmax -> top2 -> counts ----------------
__global__ __launch_bounds__(256)
void gate_k(const float* __restrict__ text, const float* __restrict__ G3,
            const float* __restrict__ gb, float* __restrict__ gate_out,
            int* __restrict__ topIdx, float* __restrict__ topW,
            int* __restrict__ counts)
{
  __shared__ __align__(16) float sT[E_DIM];
  __shared__ float lg[8];
  int b = blockIdx.x, t = threadIdx.x;
  *(f32x4*)&sT[t * 4] = *(const f32x4*)&text[(size_t)b * E_DIM + t * 4];
  __syncthreads();
  int wave = t >> 6, lane = t & 63;
  #pragma unroll
  for (int ei = 0; ei < 2; ++ei) {
    int e = wave * 2 + ei;
    float s = 0.f;
    for (int k = lane; k < E_DIM; k += 64) s = __builtin_fmaf(sT[k], G3[k * 8 + e], s);
    #pragma unroll
    for (int off = 32; off; off >>= 1) s += __shfl_down(s, off);
    if (lane == 0) lg[e] = s + gb[e];
  }
  __syncthreads();
  if (t == 0) {
    float p[8];
    float mx = lg[0];
    for (int i = 1; i < 8; i++) mx = fmaxf(mx, lg[i]);
    float den = 0.f;
    for (int i = 0; i < 8; i++) { p[i] = __expf(lg[i] - mx); den += p[i]; }
    float inv = 1.f / den;
    for (int i = 0; i < 8; i++) { p[i] *= inv; gate_out[(size_t)b * 8 + i] = p[i]; }
    int i1 = 0;
    for (int i = 1; i < 8; i++) if (p[i] > p[i1]) i1 = i;       // ties -> lower index
    int i2 = (i1 == 0) ? 1 : 0;
    for (int i = 0; i < 8; i++) if (i != i1 && p[i] > p[i2]) i2 = i;
    float ex = __expf(p[i2] - p[i1]);                            // softmax over top-2 probs
    float w1 = 1.f / (1.f + ex), w2 = ex / (1.f + ex);
    topIdx[b * 2] = i1; topIdx[b * 2 + 1] = i2;
    topW[b * 2] = w1;  topW[b * 2 + 1] = w2;
    atomicAdd(&counts[i1], 1);
    atomicAdd(&counts[i2], 1);
  }
}

__global__ void imp_k(const float* __restrict__ gate_out, float* __restrict__ imp)
{
  int e = blockIdx.x, t = threadIdx.x;
  float s = 0.f;
  for (int b = t; b < B_TOK; b += 256) s += gate_out[(size_t)b * 8 + e];
  __shared__ float red[256];
  red[t] = s; __syncthreads();
  for (int off = 128; off; off >>= 1) { if (t < off) red[t] += red[t + off]; __syncthreads(); }
  if (t == 0) imp[e] = red[0];
}

__global__ void loss_k(const float* __restrict__ imp, float* __restrict__ out_loss)
{
  if (threadIdx.x == 0 && blockIdx.x == 0) {
    float m = 0.f;
    for (int e = 0; e < 8; e++) m += imp[e];
    m *= 0.125f;
    float v = 0.f;
    for (int e = 0; e < 8; e++) { float d = imp[e] - m; v += d * d; }
    v /= 7.f;                                  // ddof=1
    out_loss[0] = 0.01f * v / (m * m);
  }
}

__global__ void zero_k(int* counts, int* cursor)
{
  int t = threadIdx.x;
  if (t < 8) { counts[t] = 0; cursor[t] = 0; }
}

// prefix-scan + compact 128-row tile table: meta = {nT, (e, rowBase, rows)*}
__global__ void scan_k(const int* __restrict__ counts, int* __restrict__ bases,
                       int* __restrict__ meta)
{
  if (threadIdx.x == 0) {
    int a = 0, nt = 0;
    for (int e = 0; e < 8; e++) {
      bases[e] = a;
      int c = counts[e];
      for (int j = 0; j < c; j += 128) {
        meta[1 + 3 * nt] = e;
        meta[2 + 3 * nt] = a + j;
        meta[3 + 3 * nt] = (c - j < 128) ? (c - j) : 128;
        nt++;
      }
      a += c;
    }
    meta[0] = nt;
  }
}

__global__ void fill_k(const int* __restrict__ topIdx, int* __restrict__ cursor,
                       const int* __restrict__ bases, int* __restrict__ perm,
                       int* __restrict__ slotOf)
{
  int b = blockIdx.x * 256 + threadIdx.x;
  if (b < B_TOK) {
    #pragma unroll
    for (int j = 0; j < 2; j++) {
      int e = topIdx[b * 2 + j];
      int pos = atomicAdd(&cursor[e], 1);
      int slot = bases[e] + pos;
      perm[slot] = b;
      slotOf[b * 2 + j] = slot;
    }
  }
}

// combine split-K expert partials + per-expert bias, weighted top-2 mix
__global__ __launch_bounds__(256)
void combine_k(const float* __restrict__ Yp, const int* __restrict__ slotOf,
               const int* __restrict__ topIdx, const float* __restrict__ topW,
               const float* __restrict__ b2, float* __restrict__ y)
{
  int b = blockIdx.x, t = threadIdx.x;
  int s0 = slotOf[b * 2], s1 = slotOf[b * 2 + 1];
  int e0 = topIdx[b * 2], e1 = topIdx[b * 2 + 1];
  float w0 = topW[b * 2], w1 = topW[b * 2 + 1];
  int c = t * 4;
  size_t P1 = (size_t)NSLOT * E_DIM;
  f32x4 x0 = *(const f32x4*)&Yp[(size_t)s0 * E_DIM + c];
  x0 += *(const f32x4*)&Yp[P1 + (size_t)s0 * E_DIM + c];
  x0 += *(const f32x4*)&b2[(size_t)e0 * E_DIM + c];
  f32x4 x1 = *(const f32x4*)&Yp[(size_t)s1 * E_DIM + c];
  x1 += *(const f32x4*)&Yp[P1 + (size_t)s1 * E_DIM + c];
  x1 += *(const f32x4*)&b2[(size_t)e1 * E_DIM + c];
  f32x4 r = x0 * w0 + x1 * w1;
  *(f32x4*)&y[(size_t)b * E_DIM + c] = r;
}

// ---------------- host ----------------
extern "C" void kernel_launch(void* const* d_in, const int* in_sizes, int n_in,
                              void* d_out, int out_size, void* d_ws, size_t ws_size,
                              hipStream_t stream)
{
  (void)in_sizes; (void)n_in; (void)out_size;
  const float* src   = (const float*)d_in[0];
  const float* tgt   = (const float*)d_in[1];
  const float* bgr   = (const float*)d_in[2];
  const float* image = (const float*)d_in[3];
  const float* text  = (const float*)d_in[4];
  const float* W_enc = (const float*)d_in[5];
  const float* b_enc = (const float*)d_in[6];
  const float* W_img = (const float*)d_in[7];
  const float* b_img = (const float*)d_in[8];
  // d_in[9..12]: Wq,bq,Wk,bk — dead (softmax over length-1 key axis == 1)
  const float* Wv    = (const float*)d_in[13];
  const float* bv    = (const float*)d_in[14];
  const float* Wo    = (const float*)d_in[15];
  const float* bo    = (const float*)d_in[16];
  const float* Wg    = (const float*)d_in[17];
  const float* bgg   = (const float*)d_in[18];
  const float* W1    = (const float*)d_in[19];
  const float* b1    = (const float*)d_in[20];
  const float* W2    = (const float*)d_in[21];
  const float* b2    = (const float*)d_in[22];

  float* out_y    = (float*)d_out;
  float* out_gate = out_y + (size_t)B_TOK * E_DIM;
  float* out_loss = out_gate + (size_t)B_TOK * N_EXPC;

  char* p = (char*)d_ws;
  auto alloc = [&](size_t bytes) { char* r = p; p += (bytes + 255) & ~(size_t)255; return r; };
  uint16_t* WencT = (uint16_t*)alloc((size_t)256 * IMGSZ * 2);
  uint16_t* WimgT = (uint16_t*)alloc((size_t)256 * E_DIM * 2);
  uint16_t* W1T   = (uint16_t*)alloc((size_t)N_EXPC * HID * E_DIM * 2);
  uint16_t* W2T   = (uint16_t*)alloc((size_t)N_EXPC * E_DIM * HID * 2);
  float* part  = (float*)alloc((size_t)8 * E_DIM * 4);
  float* g1c   = (float*)alloc((size_t)E_DIM * 8 * 4);
  float* G3    = (float*)alloc((size_t)E_DIM * 8 * 4);
  float* t1    = (float*)alloc(E_DIM * 4);
  float* gbv   = (float*)alloc(64 * 4);
  float* impb  = (float*)alloc(64 * 4);
  int*   topIdx = (int*)alloc(B_TOK * 2 * 4);
  float* topW   = (float*)alloc(B_TOK * 2 * 4);
  int*   slotOf = (int*)alloc(B_TOK * 2 * 4);
  int*   counts = (int*)alloc(64 * 4);
  int*   bases  = (int*)alloc(64 * 4);
  int*   cursor = (int*)alloc(64 * 4);
  int*   meta   = (int*)alloc((1 + 3 * (NTIL + 1)) * 4 + 64);
  int*   perm   = (int*)alloc(NSLOT * 4);
  uint16_t* xbf  = (uint16_t*)alloc((size_t)B_TOK * E_DIM * 2);
  uint16_t* Hbuf = (uint16_t*)alloc((size_t)NSLOT * HID * 2);
  // union region: enc partials (56 MB) then expert split-K partials Yp (64 MB)
  char* uni = alloc((size_t)2 * NSLOT * E_DIM * 4);
  float* Penc = (float*)uni;                               // 12 planes * 4 MB
  float* Pimg = Penc + (size_t)12 * B_TOK * 256;           // 2 planes
  float* Yp   = (float*)uni;                               // reused after redu_k
  if ((size_t)(p - (char*)d_ws) > ws_size) return;   // ws too small: fail visibly

  zero_k<<<1, 64, 0, stream>>>(counts, cursor);

  // weight transposes (f32 [R][C] -> bf16 [C][R])
  transpose64<<<dim3(256 / 64, IMGSZ / 64, 1), 256, 0, stream>>>(W_enc, WencT, IMGSZ, 256);
  transpose64<<<dim3(256 / 64, E_DIM / 64, 1), 256, 0, stream>>>(W_img, WimgT, E_DIM, 256);
  transpose64<<<dim3(HID / 64, E_DIM / 64, 8), 256, 0, stream>>>(W1, W1T, E_DIM, HID);
  transpose64<<<dim3(E_DIM / 64, HID / 64, 8), 256, 0, stream>>>(W2, W2T, HID, E_DIM);

  // gate fold (f32, precision-critical): logits = text@(Wv@(Wo@Wg)) + ((bv@Wo+bo)@Wg + bg)
  bvwo_k<<<8, 256, 0, stream>>>(bv, Wo, part);
  t1red_k<<<4, 256, 0, stream>>>(part, bo, t1);
  matf_k<<<256, 256, 0, stream>>>(Wo, Wg, g1c);
  matf_k<<<256, 256, 0, stream>>>(Wv, g1c, G3);
  gbias_k<<<1, 512, 0, stream>>>(t1, Wg, bgg, gbv);
  gate_k<<<B_TOK, 256, 0, stream>>>(text, G3, gbv, out_gate, topIdx, topW, counts);
  imp_k<<<8, 256, 0, stream>>>(out_gate, impb);
  loss_k<<<1, 64, 0, stream>>>(impb, out_loss);
  scan_k<<<1, 64, 0, stream>>>(counts, bases, meta);
  fill_k<<<16, 256, 0, stream>>>(topIdx, cursor, bases, perm, slotOf);

  // visionFeatures x = [enc(s)|enc(t)|enc(bg)|silu(img@W_img+b)]  (reg-A streaming GEMM)
  gemm_encR<4><<<dim3(B_TOK / 64, 2, 12), 256, 0, stream>>>(
      src, tgt, bgr, IMGSZ, WencT, Penc, IMGSZ);
  gemm_encR<2><<<dim3(B_TOK / 64, 2, 2), 256, 0, stream>>>(
      image, image, image, E_DIM, WimgT, Pimg, E_DIM);
  redu_k<4, false><<<dim3(B_TOK / 4, 3), 256, 0, stream>>>(Penc, b_enc, xbf, 0);
  redu_k<2, true><<<dim3(B_TOK / 4, 1), 256, 0, stream>>>(Pimg, b_img, xbf, 768);

  // sparse top-2 expert MLPs: 128^2, 2-buffer depth-1, 5 blocks/CU; L2 split-K=2
  gemm_p<128, 3, true, HID / 128, 1><<<dim3(NTIL * (HID / 128)), 256, 0, stream>>>(
      xbf, E_DIM, W1T, Hbuf, HID, b1, E_DIM, meta, perm, (size_t)HID * E_DIM, HID, 0);
  gemm_p<128, 0, false, E_DIM / 128, 2><<<dim3(NTIL * (E_DIM / 128) * 2), 256, 0, stream>>>(
      Hbuf, HID, W2T, Yp, E_DIM, b2, HID, meta, perm, (size_t)E_DIM * HID, E_DIM,
      (size_t)NSLOT * E_DIM);

  combine_k<<<B_TOK, 256, 0, stream>>>(Yp, slotOf, topIdx, topW, b2, out_y);
}

// Round 10
// 709.547 us; speedup vs baseline: 1.0088x; 1.0088x over previous
//
#include <hip/hip_runtime.h>
#include <hip/hip_bf16.h>
#include <stdint.h>

typedef __bf16 bf16_t;
typedef bf16_t bf16x8 __attribute__((ext_vector_type(8)));
typedef float f32x4 __attribute__((ext_vector_type(4)));
typedef uint16_t u16x8 __attribute__((ext_vector_type(8)));

static constexpr int B_TOK  = 4096;
static constexpr int E_DIM  = 1024;
static constexpr int N_EXPC = 8;
static constexpr int HID    = 4096;
static constexpr int IMGSZ  = 4096;
static constexpr int NSLOT  = 2 * B_TOK;
static constexpr int NTIL   = 71;          // max 128-row tiles: 64 + 7 remainder tiles

#define DEVI __device__ __forceinline__

DEVI int imin(int a, int b) { return a < b ? a : b; }

DEVI uint16_t f2bf(float f) {
  union { float f; uint32_t u; } v; v.f = f;
  uint32_t u = v.u;
  return (uint16_t)((u + 0x7FFFu + ((u >> 16) & 1u)) >> 16);
}

DEVI void gload_lds16(const void* g, void* l) {
  __builtin_amdgcn_global_load_lds((const __attribute__((address_space(1))) void*)g,
                                   (__attribute__((address_space(3))) void*)l, 16, 0, 0);
}

template<int N> DEVI void waitv() {
  if constexpr (N == 0)       asm volatile("s_waitcnt vmcnt(0)" ::: "memory");
  else if constexpr (N == 3)  asm volatile("s_waitcnt vmcnt(3)" ::: "memory");
  else if constexpr (N == 4)  asm volatile("s_waitcnt vmcnt(4)" ::: "memory");
  else if constexpr (N == 10) asm volatile("s_waitcnt vmcnt(10)" ::: "memory");
}

#define BAR() do { __builtin_amdgcn_sched_barrier(0); __builtin_amdgcn_s_barrier(); \
                   __builtin_amdgcn_sched_barrier(0); } while (0)

#define MFMA16(a, b, c) __builtin_amdgcn_mfma_f32_16x16x32_bf16((a), (b), (c), 0, 0, 0)

// ============ merged weight transpose: f32 [R][C] -> bf16 [C][R], all 4 weights ============
// Coalesced reads (f32x4/lane) and coalesced writes (u16x8 = 16B/lane; lanes j=0..7
// cover one contiguous 128B output-row segment). One dispatch for W1, W2, W_enc, W_img.
__global__ __launch_bounds__(256)
void transW(const float* __restrict__ W1, const float* __restrict__ W2,
            const float* __restrict__ We, const float* __restrict__ Wi,
            uint16_t* __restrict__ W1T, uint16_t* __restrict__ W2T,
            uint16_t* __restrict__ WeT, uint16_t* __restrict__ WiT)
{
  __shared__ float tile[64][65];
  int bid = blockIdx.x;
  const float* in; uint16_t* out; int R, C, c0, r0;
  if (bid < 8192) {                       // W1: 8 x [1024][4096]
    int e = bid >> 10, rem = bid & 1023;
    R = 1024; C = 4096;
    c0 = (rem & 63) * 64; r0 = (rem >> 6) * 64;
    in = W1 + (size_t)e * R * C; out = W1T + (size_t)e * R * C;
  } else if (bid < 16384) {               // W2: 8 x [4096][1024]
    int i = bid - 8192; int e = i >> 10, rem = i & 1023;
    R = 4096; C = 1024;
    c0 = (rem & 15) * 64; r0 = (rem >> 4) * 64;
    in = W2 + (size_t)e * R * C; out = W2T + (size_t)e * R * C;
  } else if (bid < 16640) {               // W_enc: [4096][256]
    int i = bid - 16384;
    R = 4096; C = 256;
    c0 = (i & 3) * 64; r0 = (i >> 2) * 64;
    in = We; out = WeT;
  } else {                                // W_img: [1024][256]
    int i = bid - 16640;
    R = 1024; C = 256;
    c0 = (i & 3) * 64; r0 = (i >> 2) * 64;
    in = Wi; out = WiT;
  }
  int t = threadIdx.x;
  #pragma unroll
  for (int i = 0; i < 4; ++i) {
    int rr = i * 16 + (t >> 4), c4 = (t & 15) * 4;
    f32x4 v = *(const f32x4*)&in[(size_t)(r0 + rr) * C + c0 + c4];
    tile[rr][c4 + 0] = v[0]; tile[rr][c4 + 1] = v[1];
    tile[rr][c4 + 2] = v[2]; tile[rr][c4 + 3] = v[3];
  }
  __syncthreads();
  #pragma unroll
  for (int i = 0; i < 2; ++i) {
    int c = i * 32 + (t >> 3), j = t & 7;
    u16x8 o;
    #pragma unroll
    for (int k = 0; k < 8; ++k) o[k] = f2bf(tile[j * 8 + k][c]);
    *(u16x8*)&out[(size_t)(c0 + c) * R + r0 + j * 8] = o;
  }
}

// ================= expert GEMM: 128x128, 2-buffer depth-1 counted-vmcnt ==========
// C[M,N] = A[M,K] @ BT[N,K]^T (+bias, +activation)
// EPI: 0 = raw f32 split-K partial (no bias), 3 = bias + gelu(exp-form) -> bf16
template<int BN, int EPI, bool GATHER, int NT, int KSPLIT>
__global__ __launch_bounds__(256, 5)
void gemm_p(const uint16_t* __restrict__ Ab, int lda,
            const uint16_t* __restrict__ BT, void* __restrict__ Cv, int ldc,
            const float* __restrict__ bias, int K,
            const int* __restrict__ meta, const int* __restrict__ perm,
            size_t bStride, int biasStride, size_t cPlane)
{
  constexpr int HN = BN / 2, FN = BN / 32;
  constexpr int OPS = (BN == 128 ? 4 : 3);
  constexpr int NT2 = NT * KSPLIT;
  constexpr int TOTAL = NTIL * NT2, Q = TOTAL / 8, FULLB = 64 * NT2;
  int bid = blockIdx.x;
  int wg = (bid & 7) * Q + (bid >> 3);            // XCD swizzle
  int mtile, nt2;
  if (wg < FULLB) { int rem = wg % (8 * NT2); mtile = (wg / (8 * NT2)) * 8 + (rem & 7); nt2 = rem >> 3; }
  else            { int rem = wg - FULLB;     mtile = 64 + rem % 7;                     nt2 = rem / 7; }
  if (mtile >= meta[0]) return;
  int nt = nt2 % NT, kc = nt2 / NT;
  int e = meta[1 + 3 * mtile], rowBase = meta[2 + 3 * mtile], rows = meta[3 + 3 * mtile];
  int Kc = K / KSPLIT, k0 = kc * Kc;
  const uint16_t* Bt = BT + (size_t)e * bStride;
  const float* bi = bias + (size_t)e * (size_t)biasStride;

  constexpr int ABUF = 8192;
  constexpr int BBUF = (BN == 128) ? 8192 : 4096;
  __shared__ __align__(16) char sAraw[2 * ABUF];
  __shared__ __align__(16) char sBraw[2 * BBUF];

  int t = threadIdx.x, wave = t >> 6, lane = t & 63;
  int wr = wave >> 1, wc = wave & 1;

  int rB = t >> 2;
  int slB = ((t & 3) ^ (rB & 3)) * 8;
  const uint16_t* gB0 = Bt + (size_t)(nt * BN + rB) * K + k0 + slB;
  const uint16_t* gB1 = Bt + (size_t)(nt * BN + rB + 64) * K + k0 + slB;  // BN==128 only

  int r0 = t >> 2, r1 = r0 + 64;
  int sl = ((t & 3) ^ (r0 & 3)) * 8;
  int rr0 = imin(r0, rows - 1), rr1 = imin(r1, rows - 1);
  int car0 = GATHER ? perm[rowBase + rr0] : rowBase + rr0;
  int car1 = GATHER ? perm[rowBase + rr1] : rowBase + rr1;
  const uint16_t* gA0 = Ab + (size_t)car0 * lda + k0 + sl;
  const uint16_t* gA1 = Ab + (size_t)car1 * lda + k0 + sl;

  char* laW = sAraw + wave * 1024;
  char* lbW = sBraw + wave * 1024;
  auto STAGE = [&](int kt, int c) {
    int ko = kt << 5;
    char* la = laW + c * ABUF;
    char* lb = lbW + c * BBUF;
    gload_lds16(gA0 + ko, la);
    gload_lds16(gA1 + ko, la + 4096);
    gload_lds16(gB0 + ko, lb);
    if constexpr (BN == 128) gload_lds16(gB1 + ko, lb + 4096);
  };

  f32x4 acc[4][FN];
  #pragma unroll
  for (int m = 0; m < 4; m++)
    #pragma unroll
    for (int n = 0; n < FN; n++)
      acc[m][n] = f32x4{0.f, 0.f, 0.f, 0.f};

  STAGE(0, 0);

  int fr = lane & 15;
  int rdoff = ((lane >> 4) ^ (lane & 3)) * 16;
  int nk = Kc >> 5;

  for (int kt = 0; kt < nk; ++kt) {
    int b = kt & 1, nb = b ^ 1;
    bool more = kt + 1 < nk;
    if (more) { STAGE(kt + 1, nb); waitv<OPS>(); }   // tile kt retired; kt+1 in flight
    else waitv<0>();
    BAR();

    const char* bA = sAraw + b * ABUF;
    const char* bB = sBraw + b * BBUF;
    bf16x8 af[4], bfr[FN];
    #pragma unroll
    for (int m = 0; m < 4; m++)
      af[m] = *(const bf16x8*)(bA + (wr * 64 + m * 16 + fr) * 64 + rdoff);
    #pragma unroll
    for (int n = 0; n < FN; n++)
      bfr[n] = *(const bf16x8*)(bB + (wc * HN + n * 16 + fr) * 64 + rdoff);
    #pragma unroll
    for (int m = 0; m < 4; m++)
      #pragma unroll
      for (int n = 0; n < FN; n++)
        acc[m][n] = MFMA16(af[m], bfr[n], acc[m][n]);

    BAR();
  }

  // epilogue: C/D layout col=lane&15, row=(lane>>4)*4+reg (m89-verified)
  #pragma unroll
  for (int m = 0; m < 4; m++) {
    int lrow = wr * 64 + m * 16 + (lane >> 4) * 4;
    #pragma unroll
    for (int n = 0; n < FN; n++) {
      int col = nt * BN + wc * HN + n * 16 + (lane & 15);
      float bval = (EPI == 3) ? bi[col] : 0.f;
      #pragma unroll
      for (int r = 0; r < 4; r++) {
        int lr = lrow + r;
        if (lr >= rows) continue;
        float v = acc[m][n][r] + bval;
        size_t cr = (size_t)kc * cPlane + (size_t)(rowBase + lr) * ldc + col;
        if (EPI == 3) {   // gelu(tanh) == v * sigmoid(1.5957691*(v + 0.044715 v^3))
          float u = v + 0.044715f * v * v * v;
          v = v / (1.f + __expf(-1.5957691216057308f * u));
          ((uint16_t*)Cv)[cr] = f2bf(v);
        } else {
          ((float*)Cv)[cr] = v;
        }
      }
    }
  }
}

// ================= enc/img GEMM: reg-A streaming (memory-bound regime) =================
template<int SPLITK>
__global__ __launch_bounds__(256, 3)
void gemm_encR(const float* __restrict__ F0, const float* __restrict__ F1,
               const float* __restrict__ F2, int lda,
               const uint16_t* __restrict__ BT, float* __restrict__ P, int K)
{
  int z = blockIdx.z, br = z / SPLITK, kc = z % SPLITK;
  const float* Af = (br == 0) ? F0 : (br == 1) ? F1 : F2;
  int Kc = K / SPLITK, k0 = kc * Kc;
  int rowBase = blockIdx.x * 64, nt = blockIdx.y;

  __shared__ __align__(16) char sB[3 * 8192];
  int t = threadIdx.x, wave = t >> 6, lane = t & 63;
  int fr = lane & 15, q4 = lane >> 4;

  const float* gA = Af + (size_t)(rowBase + wave * 16 + fr) * lda + k0 + q4 * 8;

  int rloc = t >> 2;
  int ssw = ((t & 3) ^ (rloc & 3)) * 8;
  const uint16_t* gB0 = BT + (size_t)(nt * 128 + rloc) * K + k0 + ssw;
  const uint16_t* gB1 = gB0 + (size_t)64 * K;

  auto STB = [&](int kt, int c) {
    gload_lds16(gB0 + kt * 32, sB + c * 8192 + wave * 1024);
    gload_lds16(gB1 + kt * 32, sB + c * 8192 + 4096 + wave * 1024);
  };

  f32x4 acc[8];
  #pragma unroll
  for (int n = 0; n < 8; ++n) acc[n] = f32x4{0.f, 0.f, 0.f, 0.f};

  int nk = Kc >> 5;
  STB(0, 0); STB(1, 1);
  f32x4 aE0 = *(const f32x4*)(gA),      aE1 = *(const f32x4*)(gA + 4);
  f32x4 aO0 = *(const f32x4*)(gA + 32), aO1 = *(const f32x4*)(gA + 36);
  int c0 = 0, c2 = 2;
  int bRow = (q4 ^ (fr & 3)) * 16;

  auto step = [&](int kt, f32x4& aX0, f32x4& aX1) {
    bool m2 = kt + 2 < nk;
    if (m2) STB(kt + 2, c2);
    bf16x8 a;
    a[0] = (bf16_t)aX0[0]; a[1] = (bf16_t)aX0[1]; a[2] = (bf16_t)aX0[2]; a[3] = (bf16_t)aX0[3];
    a[4] = (bf16_t)aX1[0]; a[5] = (bf16_t)aX1[1]; a[6] = (bf16_t)aX1[2]; a[7] = (bf16_t)aX1[3];
    int kp = m2 ? kt + 2 : kt;
    aX0 = *(const f32x4*)(gA + kp * 32);
    aX1 = *(const f32x4*)(gA + kp * 32 + 4);
    if (m2) waitv<10>(); else waitv<0>();
    BAR();
    const char* bb = sB + c0 * 8192;
    bf16x8 bfr[8];
    #pragma unroll
    for (int n = 0; n < 8; ++n)
      bfr[n] = *(const bf16x8*)(bb + n * 1024 + fr * 64 + bRow);
    #pragma unroll
    for (int n = 0; n < 8; ++n) acc[n] = MFMA16(a, bfr[n], acc[n]);
    BAR();
    c0 = (c0 == 2) ? 0 : c0 + 1;
    c2 = (c2 == 2) ? 0 : c2 + 1;
  };

  for (int kt = 0; kt < nk; kt += 2) {
    step(kt, aE0, aE1);
    step(kt + 1, aO0, aO1);
  }

  #pragma unroll
  for (int n = 0; n < 8; ++n) {
    int col = nt * 128 + n * 16 + fr;
    #pragma unroll
    for (int r = 0; r < 4; ++r) {
      int row = rowBase + wave * 16 + q4 * 4 + r;
      P[((size_t)z * B_TOK + row) * 256 + col] = acc[n][r];
    }
  }
}

// reduce split-K partials + bias (+silu) -> bf16 columns of xbf
template<int SK, bool SILU>
__global__ __launch_bounds__(256)
void redu_k(const float* __restrict__ P, const float* __restrict__ bias,
            uint16_t* __restrict__ xb, int colBase)
{
  int br = blockIdx.y;
  int row = blockIdx.x * 4 + (threadIdx.x >> 6);
  int c4 = (threadIdx.x & 63) * 4;
  f32x4 s = *(const f32x4*)&bias[c4];
  const float* p = P + ((size_t)br * SK * B_TOK + row) * 256 + c4;
  #pragma unroll
  for (int kc = 0; kc < SK; ++kc)
    s += *(const f32x4*)(p + (size_t)kc * B_TOK * 256);
  if (SILU) {
    #pragma unroll
    for (int j = 0; j < 4; ++j) s[j] = s[j] / (1.f + __expf(-s[j]));
  }
  ushort4 o;
  o.x = f2bf(s[0]); o.y = f2bf(s[1]); o.z = f2bf(s[2]); o.w = f2bf(s[3]);
  *(ushort4*)&xb[(size_t)row * E_DIM + colBase + br * 256 + c4] = o;
}

// ---------------- gate-path fold (all f32, parallelized) ----------------
__global__ __launch_bounds__(256)
void bvwo_k(const float* __restrict__ bv, const float* __restrict__ Wo,
            float* __restrict__ part)
{
  int b = blockIdx.x, t = threadIdx.x;
  f32x4 acc = {0.f, 0.f, 0.f, 0.f};
  for (int k = b * 128; k < b * 128 + 128; ++k) {
    float s = bv[k];
    f32x4 w = *(const f32x4*)&Wo[(size_t)k * E_DIM + t * 4];
    acc[0] = __builtin_fmaf(s, w[0], acc[0]);
    acc[1] = __builtin_fmaf(s, w[1], acc[1]);
    acc[2] = __builtin_fmaf(s, w[2], acc[2]);
    acc[3] = __builtin_fmaf(s, w[3], acc[3]);
  }
  *(f32x4*)&part[(size_t)b * E_DIM + t * 4] = acc;
}

__global__ void t1red_k(const float* __restrict__ part, const float* __restrict__ bo,
                        float* __restrict__ t1)
{
  int j = blockIdx.x * 256 + threadIdx.x;
  float s = bo[j];
  for (int b = 0; b < 8; ++b) s += part[(size_t)b * E_DIM + j];
  t1[j] = s;
}

__global__ __launch_bounds__(256)
void matf_k(const float* __restrict__ W, const float* __restrict__ G,
            float* __restrict__ out)
{
  int k = blockIdx.x * 4 + (threadIdx.x >> 6);
  int lane = threadIdx.x & 63;
  float a0 = 0.f, a1 = 0.f, a2 = 0.f, a3 = 0.f, a4 = 0.f, a5 = 0.f, a6 = 0.f, a7 = 0.f;
  for (int m = lane; m < E_DIM; m += 64) {
    float w = W[(size_t)k * E_DIM + m];
    const float* gm = &G[m * 8];
    a0 = __builtin_fmaf(w, gm[0], a0); a1 = __builtin_fmaf(w, gm[1], a1);
    a2 = __builtin_fmaf(w, gm[2], a2); a3 = __builtin_fmaf(w, gm[3], a3);
    a4 = __builtin_fmaf(w, gm[4], a4); a5 = __builtin_fmaf(w, gm[5], a5);
    a6 = __builtin_fmaf(w, gm[6], a6); a7 = __builtin_fmaf(w, gm[7], a7);
  }
  #pragma unroll
  for (int off = 32; off; off >>= 1) {
    a0 += __shfl_xor(a0, off); a1 += __shfl_xor(a1, off);
    a2 += __shfl_xor(a2, off); a3 += __shfl_xor(a3, off);
    a4 += __shfl_xor(a4, off); a5 += __shfl_xor(a5, off);
    a6 += __shfl_xor(a6, off); a7 += __shfl_xor(a7, off);
  }
  if (lane == 0) {
    float* o = &out[k * 8];
    o[0] = a0; o[1] = a1; o[2] = a2; o[3] = a3;
    o[4] = a4; o[5] = a5; o[6] = a6; o[7] = a7;
  }
}

__global__ __launch_bounds__(512)
void gbias_k(const float* __restrict__ t1, const float* __restrict__ Wg,
             const float* __restrict__ bg, float* __restrict__ gb)
{
  int e = threadIdx.x >> 6, lane = threadIdx.x & 63;
  float s = 0.f;
  for (int m = lane; m < E_DIM; m += 64) s = __builtin_fmaf(t1[m], Wg[m * 8 + e], s);
  #pragma unroll
  for (int off = 32; off; off >>= 1) s += __shfl_xor(s, off);
  if (lane == 0) gb[e] = s + bg[e];
}

// ---------------- gate: logits -> softmax -> top2 -> counts ----------------
__global__ __launch_bounds__(256)
void gate_k(const float* __restrict__ text, const float* __restrict__ G3,
            const float* __restrict__ gb, float* __restrict__ gate_out,
            int* __restrict__ topIdx, float* __restrict__ topW,
            int* __restrict__ counts)
{
  __shared__ __align__(16) float sT[E_DIM];
  __shared__ float lg[8];
  int b = blockIdx.x, t = threadIdx.x;
  *(f32x4*)&sT[t * 4] = *(const f32x4*)&text[(size_t)b * E_DIM + t * 4];
  __syncthreads();
  int wave = t >> 6, lane = t & 63;
  #pragma unroll
  for (int ei = 0; ei < 2; ++ei) {
    int e = wave * 2 + ei;
    float s = 0.f;
    for (int k = lane; k < E_DIM; k += 64) s = __builtin_fmaf(sT[k], G3[k * 8 + e], s);
    #pragma unroll
    for (int off = 32; off; off >>= 1) s += __shfl_down(s, off);
    if (lane == 0) lg[e] = s + gb[e];
  }
  __syncthreads();
  if (t == 0) {
    float p[8];
    float mx = lg[0];
    for (int i = 1; i < 8; i++) mx = fmaxf(mx, lg[i]);
    float den = 0.f;
    for (int i = 0; i < 8; i++) { p[i] = __expf(lg[i] - mx); den += p[i]; }
    float inv = 1.f / den;
    for (int i = 0; i < 8; i++) { p[i] *= inv; gate_out[(size_t)b * 8 + i] = p[i]; }
    int i1 = 0;
    for (int i = 1; i < 8; i++) if (p[i] > p[i1]) i1 = i;       // ties -> lower index
    int i2 = (i1 == 0) ? 1 : 0;
    for (int i = 0; i < 8; i++) if (i != i1 && p[i] > p[i2]) i2 = i;
    float ex = __expf(p[i2] - p[i1]);                            // softmax over top-2 probs
    float w1 = 1.f / (1.f + ex), w2 = ex / (1.f + ex);
    topIdx[b * 2] = i1; topIdx[b * 2 + 1] = i2;
    topW[b * 2] = w1;  topW[b * 2 + 1] = w2;
    atomicAdd(&counts[i1], 1);
    atomicAdd(&counts[i2], 1);
  }
}

__global__ void imp_k(const float* __restrict__ gate_out, float* __restrict__ imp)
{
  int e = blockIdx.x, t = threadIdx.x;
  float s = 0.f;
  for (int b = t; b < B_TOK; b += 256) s += gate_out[(size_t)b * 8 + e];
  __shared__ float red[256];
  red[t] = s; __syncthreads();
  for (int off = 128; off; off >>= 1) { if (t < off) red[t] += red[t + off]; __syncthreads(); }
  if (t == 0) imp[e] = red[0];
}

__global__ void loss_k(const float* __restrict__ imp, float* __restrict__ out_loss)
{
  if (threadIdx.x == 0 && blockIdx.x == 0) {
    float m = 0.f;
    for (int e = 0; e < 8; e++) m += imp[e];
    m *= 0.125f;
    float v = 0.f;
    for (int e = 0; e < 8; e++) { float d = imp[e] - m; v += d * d; }
    v /= 7.f;                                  // ddof=1
    out_loss[0] = 0.01f * v / (m * m);
  }
}

__global__ void zero_k(int* counts, int* cursor)
{
  int t = threadIdx.x;
  if (t < 8) { counts[t] = 0; cursor[t] = 0; }
}

// prefix-scan + compact 128-row tile table: meta = {nT, (e, rowBase, rows)*}
__global__ void scan_k(const int* __restrict__ counts, int* __restrict__ bases,
                       int* __restrict__ meta)
{
  if (threadIdx.x == 0) {
    int a = 0, nt = 0;
    for (int e = 0; e < 8; e++) {
      bases[e] = a;
      int c = counts[e];
      for (int j = 0; j < c; j += 128) {
        meta[1 + 3 * nt] = e;
        meta[2 + 3 * nt] = a + j;
        meta[3 + 3 * nt] = (c - j < 128) ? (c - j) : 128;
        nt++;
      }
      a += c;
    }
    meta[0] = nt;
  }
}

__global__ void fill_k(const int* __restrict__ topIdx, int* __restrict__ cursor,
                       const int* __restrict__ bases, int* __restrict__ perm,
                       int* __restrict__ slotOf)
{
  int b = blockIdx.x * 256 + threadIdx.x;
  if (b < B_TOK) {
    #pragma unroll
    for (int j = 0; j < 2; j++) {
      int e = topIdx[b * 2 + j];
      int pos = atomicAdd(&cursor[e], 1);
      int slot = bases[e] + pos;
      perm[slot] = b;
      slotOf[b * 2 + j] = slot;
    }
  }
}

// combine split-K expert partials + per-expert bias, weighted top-2 mix
__global__ __launch_bounds__(256)
void combine_k(const float* __restrict__ Yp, const int* __restrict__ slotOf,
               const int* __restrict__ topIdx, const float* __restrict__ topW,
               const float* __restrict__ b2, float* __restrict__ y)
{
  int b = blockIdx.x, t = threadIdx.x;
  int s0 = slotOf[b * 2], s1 = slotOf[b * 2 + 1];
  int e0 = topIdx[b * 2], e1 = topIdx[b * 2 + 1];
  float w0 = topW[b * 2], w1 = topW[b * 2 + 1];
  int c = t * 4;
  size_t P1 = (size_t)NSLOT * E_DIM;
  f32x4 x0 = *(const f32x4*)&Yp[(size_t)s0 * E_DIM + c];
  x0 += *(const f32x4*)&Yp[P1 + (size_t)s0 * E_DIM + c];
  x0 += *(const f32x4*)&b2[(size_t)e0 * E_DIM + c];
  f32x4 x1 = *(const f32x4*)&Yp[(size_t)s1 * E_DIM + c];
  x1 += *(const f32x4*)&Yp[P1 + (size_t)s1 * E_DIM + c];
  x1 += *(const f32x4*)&b2[(size_t)e1 * E_DIM + c];
  f32x4 r = x0 * w0 + x1 * w1;
  *(f32x4*)&y[(size_t)b * E_DIM + c] = r;
}

// ---------------- host ----------------
extern "C" void kernel_launch(void* const* d_in, const int* in_sizes, int n_in,
                              void* d_out, int out_size, void* d_ws, size_t ws_size,
                              hipStream_t stream)
{
  (void)in_sizes; (void)n_in; (void)out_size;
  const float* src   = (const float*)d_in[0];
  const float* tgt   = (const float*)d_in[1];
  const float* bgr   = (const float*)d_in[2];
  const float* image = (const float*)d_in[3];
  const float* text  = (const float*)d_in[4];
  const float* W_enc = (const float*)d_in[5];
  const float* b_enc = (const float*)d_in[6];
  const float* W_img = (const float*)d_in[7];
  const float* b_img = (const float*)d_in[8];
  // d_in[9..12]: Wq,bq,Wk,bk — dead (softmax over length-1 key axis == 1)
  const float* Wv    = (const float*)d_in[13];
  const float* bv    = (const float*)d_in[14];
  const float* Wo    = (const float*)d_in[15];
  const float* bo    = (const float*)d_in[16];
  const float* Wg    = (const float*)d_in[17];
  const float* bgg   = (const float*)d_in[18];
  const float* W1    = (const float*)d_in[19];
  const float* b1    = (const float*)d_in[20];
  const float* W2    = (const float*)d_in[21];
  const float* b2    = (const float*)d_in[22];

  float* out_y    = (float*)d_out;
  float* out_gate = out_y + (size_t)B_TOK * E_DIM;
  float* out_loss = out_gate + (size_t)B_TOK * N_EXPC;

  char* p = (char*)d_ws;
  auto alloc = [&](size_t bytes) { char* r = p; p += (bytes + 255) & ~(size_t)255; return r; };
  uint16_t* WencT = (uint16_t*)alloc((size_t)256 * IMGSZ * 2);
  uint16_t* WimgT = (uint16_t*)alloc((size_t)256 * E_DIM * 2);
  uint16_t* W1T   = (uint16_t*)alloc((size_t)N_EXPC * HID * E_DIM * 2);
  uint16_t* W2T   = (uint16_t*)alloc((size_t)N_EXPC * E_DIM * HID * 2);
  float* part  = (float*)alloc((size_t)8 * E_DIM * 4);
  float* g1c   = (float*)alloc((size_t)E_DIM * 8 * 4);
  float* G3    = (float*)alloc((size_t)E_DIM * 8 * 4);
  float* t1    = (float*)alloc(E_DIM * 4);
  float* gbv   = (float*)alloc(64 * 4);
  float* impb  = (float*)alloc(64 * 4);
  int*   topIdx = (int*)alloc(B_TOK * 2 * 4);
  float* topW   = (float*)alloc(B_TOK * 2 * 4);
  int*   slotOf = (int*)alloc(B_TOK * 2 * 4);
  int*   counts = (int*)alloc(64 * 4);
  int*   bases  = (int*)alloc(64 * 4);
  int*   cursor = (int*)alloc(64 * 4);
  int*   meta   = (int*)alloc((1 + 3 * (NTIL + 1)) * 4 + 64);
  int*   perm   = (int*)alloc(NSLOT * 4);
  uint16_t* xbf  = (uint16_t*)alloc((size_t)B_TOK * E_DIM * 2);
  uint16_t* Hbuf = (uint16_t*)alloc((size_t)NSLOT * HID * 2);
  // union region: enc partials (56 MB) then expert split-K partials Yp (64 MB)
  char* uni = alloc((size_t)2 * NSLOT * E_DIM * 4);
  float* Penc = (float*)uni;                               // 12 planes * 4 MB
  float* Pimg = Penc + (size_t)12 * B_TOK * 256;           // 2 planes
  float* Yp   = (float*)uni;                               // reused after redu_k
  if ((size_t)(p - (char*)d_ws) > ws_size) return;   // ws too small: fail visibly

  zero_k<<<1, 64, 0, stream>>>(counts, cursor);

  // merged weight transposes (f32 [R][C] -> bf16 [C][R]) — one dispatch
  transW<<<dim3(16704), 256, 0, stream>>>(W1, W2, W_enc, W_img, W1T, W2T, WencT, WimgT);

  // gate fold (f32, precision-critical): logits = text@(Wv@(Wo@Wg)) + ((bv@Wo+bo)@Wg + bg)
  bvwo_k<<<8, 256, 0, stream>>>(bv, Wo, part);
  t1red_k<<<4, 256, 0, stream>>>(part, bo, t1);
  matf_k<<<256, 256, 0, stream>>>(Wo, Wg, g1c);
  matf_k<<<256, 256, 0, stream>>>(Wv, g1c, G3);
  gbias_k<<<1, 512, 0, stream>>>(t1, Wg, bgg, gbv);
  gate_k<<<B_TOK, 256, 0, stream>>>(text, G3, gbv, out_gate, topIdx, topW, counts);
  imp_k<<<8, 256, 0, stream>>>(out_gate, impb);
  loss_k<<<1, 64, 0, stream>>>(impb, out_loss);
  scan_k<<<1, 64, 0, stream>>>(counts, bases, meta);
  fill_k<<<16, 256, 0, stream>>>(topIdx, cursor, bases, perm, slotOf);

  // visionFeatures x = [enc(s)|enc(t)|enc(bg)|silu(img@W_img+b)]  (reg-A streaming GEMM)
  gemm_encR<4><<<dim3(B_TOK / 64, 2, 12), 256, 0, stream>>>(
      src, tgt, bgr, IMGSZ, WencT, Penc, IMGSZ);
  gemm_encR<2><<<dim3(B_TOK / 64, 2, 2), 256, 0, stream>>>(
      image, image, image, E_DIM, WimgT, Pimg, E_DIM);
  redu_k<4, false><<<dim3(B_TOK / 4, 3), 256, 0, stream>>>(Penc, b_enc, xbf, 0);
  redu_k<2, true><<<dim3(B_TOK / 4, 1), 256, 0, stream>>>(Pimg, b_img, xbf, 768);

  // sparse top-2 expert MLPs: 128^2, 2-buffer depth-1, 5 blocks/CU; L2 split-K=2
  gemm_p<128, 3, true, HID / 128, 1><<<dim3(NTIL * (HID / 128)), 256, 0, stream>>>(
      xbf, E_DIM, W1T, Hbuf, HID, b1, E_DIM, meta, perm, (size_t)HID * E_DIM, HID, 0);
  gemm_p<128, 0, false, E_DIM / 128, 2><<<dim3(NTIL * (E_DIM / 128) * 2), 256, 0, stream>>>(
      Hbuf, HID, W2T, Yp, E_DIM, b2, HID, meta, perm, (size_t)E_DIM * HID, E_DIM,
      (size_t)NSLOT * E_DIM);

  combine_k<<<B_TOK, 256, 0, stream>>>(Yp, slotOf, topIdx, topW, b2, out_y);
}